// Round 9
// baseline (410.173 us; speedup 1.0000x reference)
//
#include <hip/hip_runtime.h>
#include <hip/hip_fp16.h>

typedef _Float16 half8 __attribute__((ext_vector_type(8)));
typedef __attribute__((ext_vector_type(4)))  float floatx4;
typedef __attribute__((ext_vector_type(16))) float floatx16;

#define BB 32
#define CC 256
#define OO 256
#define KS 7
#define HH 31
#define WW 31
#define HO 25
#define PP 625
#define SS 49

#define SLAB_PITCH 36        // ushort elems per pos row: 32 ci + 4 pad = 72 B
#define SLAB_ROWS  310       // 64-p tile spans <= 10 x-rows; 10 x 31 = 310

// wt4 / wmod layout: [s][cb][kh][o][16ci]  (elems per (s,cb) = 2*256*16 = 8192)
#define WT4_ELEMS  ((size_t)SS * 8 * 2 * CC * 16)        // 3,211,264
#define WT4_BYTES  (WT4_ELEMS * 2)                       // 6,422,528
#define WMOD_ELEMS ((size_t)BB * WT4_ELEMS)
#define WMOD_BYTES (WMOD_ELEMS * 2)                      // 205,520,896

static __device__ __forceinline__ unsigned pk2h(float lo, float hi) {
    __half2 h = __floats2half2_rn(lo, hi);    // v_cvt_pkrtz_f16_f32
    unsigned r;
    __builtin_memcpy(&r, &h, sizeof(r));
    return r;
}
static __device__ __forceinline__ unsigned mulh2(unsigned a, unsigned b) {
    __half2 x, y;
    __builtin_memcpy(&x, &a, 4); __builtin_memcpy(&y, &b, 4);
    __half2 r = __hmul2(x, y);                // v_pk_mul_f16
    unsigned u;
    __builtin_memcpy(&u, &r, 4);
    return u;
}

// ---------------------------------------------------------------------------
// Prepass A: w[o][c][s] f32 -> wt4[s][cb][kh][o][16] fp16. Grid 392.
// ---------------------------------------------------------------------------
__global__ __launch_bounds__(256) void repack_w(const float* __restrict__ w,
                                                unsigned short* __restrict__ wt4) {
    const int bid = blockIdx.x;           // = s*8 + cb
    const int s = bid >> 3, cb = bid & 7;
    const int o = threadIdx.x;
    const float* src = w + ((size_t)o * CC + cb * 32) * SS + s;
    float v[32];
#pragma unroll
    for (int ci = 0; ci < 32; ++ci) v[ci] = src[(size_t)ci * SS];
#pragma unroll
    for (int kh = 0; kh < 2; ++kh) {
        unsigned short* dst = wt4 + ((size_t)bid * 2 + kh) * (CC * 16) + o * 16;
        uint4 p0, p1;
        p0.x = pk2h(v[kh*16+0], v[kh*16+1]);  p0.y = pk2h(v[kh*16+2], v[kh*16+3]);
        p0.z = pk2h(v[kh*16+4], v[kh*16+5]);  p0.w = pk2h(v[kh*16+6], v[kh*16+7]);
        p1.x = pk2h(v[kh*16+8], v[kh*16+9]);  p1.y = pk2h(v[kh*16+10], v[kh*16+11]);
        p1.z = pk2h(v[kh*16+12], v[kh*16+13]); p1.w = pk2h(v[kh*16+14], v[kh*16+15]);
        *(uint4*)(dst)     = p0;
        *(uint4*)(dst + 8) = p1;
    }
}

// ---------------------------------------------------------------------------
// Premod (rewritten): wmod[b][s][cb][kh][o][16] = wt4 * k. Grid 1568 = b*49+s.
// R2's premod issued 32 strided scalar k-reads PER THREAD (103M uncoalesced
// loads — its measured ~110 us). Now: k staged once per block via LDS
// (256 loads/block), fp16 pk_mul modulation, 128 KB contiguous write/block.
// ---------------------------------------------------------------------------
__global__ __launch_bounds__(256) void premod(
        const unsigned short* __restrict__ wt4, const float* __restrict__ kern,
        unsigned short* __restrict__ wmod) {
    __shared__ float kf[256];
    __shared__ unsigned kl[128];          // 256 fp16 = k[c] for this (b,s)
    const int bid = blockIdx.x;           // = b*49 + s
    const int b = bid / SS, s = bid - (bid / SS) * SS;
    const int o = threadIdx.x;
    kf[o] = kern[((size_t)b * CC + o) * SS + s];
    __syncthreads();
    if (o < 128) kl[o] = pk2h(kf[2 * o], kf[2 * o + 1]);
    __syncthreads();
#pragma unroll
    for (int cb = 0; cb < 8; ++cb) {
#pragma unroll
        for (int kh = 0; kh < 2; ++kh) {
            const size_t off = (((size_t)(s * 8 + cb) * 2 + kh) * CC + o) * 16;
            uint4 w0 = *(const uint4*)(wt4 + off);
            uint4 w1 = *(const uint4*)(wt4 + off + 8);
            uint4 k0 = *(const uint4*)(kl + cb * 16 + kh * 8);      // ci +0..7
            uint4 k1 = *(const uint4*)(kl + cb * 16 + kh * 8 + 4);  // ci +8..15
            uint4 m0, m1;
            m0.x = mulh2(w0.x, k0.x); m0.y = mulh2(w0.y, k0.y);
            m0.z = mulh2(w0.z, k0.z); m0.w = mulh2(w0.w, k0.w);
            m1.x = mulh2(w1.x, k1.x); m1.y = mulh2(w1.y, k1.y);
            m1.z = mulh2(w1.z, k1.z); m1.w = mulh2(w1.w, k1.w);
            unsigned short* dst = wmod + (size_t)b * WT4_ELEMS + off;
            *(uint4*)(dst)     = m0;
            *(uint4*)(dst + 8) = m1;
        }
    }
}

// ---------------------------------------------------------------------------
// Main (R2-verified structure, fp16, 2-deep A prefetch): block = 64o x 64p,
// 4 waves k-split (s quarters). Per s-step per wave: 4 global b128 A
// (premodulated — MFMA consumes the loaded reg DIRECTLY, the property that
// made R2 the best measured kernel; fused variants' load->pk_mul->MFMA
// chain stalled at <26% MfmaUtil across R3-R8), 4 ds b128 B (in-step),
// 8x mfma_32x32x16_f16. 2-deep A prefetch: 8 loads in flight vs R2's 4
// against ~900cy HBM latency. Grid 1280, XCD-pinned groups. lb(256,3).
// ---------------------------------------------------------------------------
__global__ __launch_bounds__(256, 3) void dwconv_big(
        const float* __restrict__ x, const unsigned short* __restrict__ wmod,
        const float* __restrict__ bias, float* __restrict__ out) {
    __shared__ unsigned short slab[SLAB_ROWS * SLAB_PITCH];   // 22320 B

    const int tid = threadIdx.x;
    const int id = blockIdx.x;
    // id = hi*80 + px*8 + g7; g = hi*8 + g7 = b*4 + oy -> same-XCD groups
    const int hi = id / 80, rem = id % 80;
    const int px = rem >> 3;
    const int g = hi * 8 + (rem & 7);
    const int b = g >> 2, oy = g & 3;

    const int p0 = px * 64, o0 = oy * 64;
    const int h0 = p0 / HO;
    const int pmax = (p0 + 63 < PP - 1) ? p0 + 63 : PP - 1;
    const int rows = pmax / HO - h0 + 7;          // <= 10
    const int npos = rows * WW;

    const int lane = tid & 63, kw = tid >> 6;
    const int l32 = lane & 31, half = lane >> 5;

    // B-fragment LDS offsets (ushort elems) for 2 p-subtiles of 32
    int bOff[2];
#pragma unroll
    for (int ph = 0; ph < 2; ++ph) {
        int p = p0 + ph * 32 + l32;
        if (p > PP - 1) p = PP - 1;               // clamp; store guarded later
        int h = p / HO, ww_ = p - h * HO;
        bOff[ph] = ((h - h0) * WW + ww_) * SLAB_PITCH + half * 8;
    }

    const int s0 = kw * 12 + (kw > 0 ? 1 : 0);    // 0,13,25,37
    const int ns = kw ? 12 : 13;

    const unsigned short* wmodb = wmod + (size_t)b * WT4_ELEMS
                                  + (size_t)(o0 + l32) * 16 + half * 8;

    floatx16 acc[2][2];
#pragma unroll
    for (int oh = 0; oh < 2; ++oh)
#pragma unroll
        for (int ph = 0; ph < 2; ++ph)
#pragma unroll
            for (int r = 0; r < 16; ++r) acc[oh][ph][r] = 0.f;

    for (int cb = 0; cb < 8; ++cb) {
        __syncthreads();   // prior compute done: slab safe to overwrite
        // ---- stage x slab: slab[pos][ci] fp16, 4 waves x 8 channels ----
        {
            const float* xsrc = x + ((size_t)(b * CC + cb * 32 + kw * 8)) * (HH * WW)
                                  + h0 * WW;
#pragma unroll
            for (int it = 0; it < 5; ++it) {
                int pos = lane + it * 64;
                if (pos < npos) {
                    float v[8];
#pragma unroll
                    for (int j = 0; j < 8; ++j) v[j] = xsrc[j * (HH * WW) + pos];
                    uint4 pkt;
                    pkt.x = pk2h(v[0], v[1]); pkt.y = pk2h(v[2], v[3]);
                    pkt.z = pk2h(v[4], v[5]); pkt.w = pk2h(v[6], v[7]);
                    *(uint4*)(slab + pos * SLAB_PITCH + kw * 8) = pkt;
                }
            }
        }
        __syncthreads();

        // rolling A pointer: frag(oh,kh) = aptr + oh*512 + kh*4096; +65536/s
        const unsigned short* aptr = wmodb + (size_t)(s0 * 8 + cb) * 8192;

        // 2-deep prefetch: wa = step s, wb = step s+1
        uint4 wa0 = *(const uint4*)(aptr);
        uint4 wa1 = *(const uint4*)(aptr + 512);
        uint4 wa2 = *(const uint4*)(aptr + 4096);
        uint4 wa3 = *(const uint4*)(aptr + 4608);
        uint4 wb0, wb1, wb2, wb3;
        if (ns > 1) {
            wb0 = *(const uint4*)(aptr + 65536);
            wb1 = *(const uint4*)(aptr + 65536 + 512);
            wb2 = *(const uint4*)(aptr + 65536 + 4096);
            wb3 = *(const uint4*)(aptr + 65536 + 4608);
        } else {
            wb0 = wa0; wb1 = wa1; wb2 = wa2; wb3 = wa3;
        }

        int s = s0, kk = s0 / KS, ll = s0 - (s0 / KS) * KS;
        for (int si = 0; si < ns; ++si) {
            // prefetch s+2
            uint4 wc0, wc1, wc2, wc3;
            if (si + 2 < ns) {
                const unsigned short* p2 = aptr + 2 * 65536;
                wc0 = *(const uint4*)(p2);
                wc1 = *(const uint4*)(p2 + 512);
                wc2 = *(const uint4*)(p2 + 4096);
                wc3 = *(const uint4*)(p2 + 4608);
            } else {
                wc0 = wb0; wc1 = wb1; wc2 = wb2; wc3 = wb3;
            }

            const unsigned short* slabS = slab + (kk * WW + ll) * SLAB_PITCH;
            half8 sb00 = *(const half8*)(slabS + bOff[0]);        // ph0 kh0
            half8 sb01 = *(const half8*)(slabS + bOff[0] + 16);   // ph0 kh1
            half8 sb10 = *(const half8*)(slabS + bOff[1]);        // ph1 kh0
            half8 sb11 = *(const half8*)(slabS + bOff[1] + 16);   // ph1 kh1

            half8 a00 = __builtin_bit_cast(half8, wa0);  // oh0 kh0
            half8 a10 = __builtin_bit_cast(half8, wa1);  // oh1 kh0
            half8 a01 = __builtin_bit_cast(half8, wa2);  // oh0 kh1
            half8 a11 = __builtin_bit_cast(half8, wa3);  // oh1 kh1

            acc[0][0] = __builtin_amdgcn_mfma_f32_32x32x16_f16(a00, sb00, acc[0][0], 0, 0, 0);
            acc[0][1] = __builtin_amdgcn_mfma_f32_32x32x16_f16(a00, sb10, acc[0][1], 0, 0, 0);
            acc[1][0] = __builtin_amdgcn_mfma_f32_32x32x16_f16(a10, sb00, acc[1][0], 0, 0, 0);
            acc[1][1] = __builtin_amdgcn_mfma_f32_32x32x16_f16(a10, sb10, acc[1][1], 0, 0, 0);
            acc[0][0] = __builtin_amdgcn_mfma_f32_32x32x16_f16(a01, sb01, acc[0][0], 0, 0, 0);
            acc[0][1] = __builtin_amdgcn_mfma_f32_32x32x16_f16(a01, sb11, acc[0][1], 0, 0, 0);
            acc[1][0] = __builtin_amdgcn_mfma_f32_32x32x16_f16(a11, sb01, acc[1][0], 0, 0, 0);
            acc[1][1] = __builtin_amdgcn_mfma_f32_32x32x16_f16(a11, sb11, acc[1][1], 0, 0, 0);

            wa0 = wb0; wa1 = wb1; wa2 = wb2; wa3 = wb3;
            wb0 = wc0; wb1 = wc1; wb2 = wc2; wb3 = wc3;
            aptr += 65536;
            ++s; if (++ll == KS) { ll = 0; ++kk; }
        }
    }

    // ---- epilogue: 4-way kw reduction via LDS (reuse slab as red[64p][68]) --
    float* red = (float*)slab;
    __syncthreads();
    if (kw == 3) {
#pragma unroll
        for (int oh = 0; oh < 2; ++oh)
#pragma unroll
            for (int ph = 0; ph < 2; ++ph)
#pragma unroll
                for (int c = 0; c < 4; ++c) {
                    floatx4 v4 = {acc[oh][ph][4*c+0], acc[oh][ph][4*c+1],
                                  acc[oh][ph][4*c+2], acc[oh][ph][4*c+3]};
                    *(floatx4*)(red + (ph * 32 + l32) * 68 + oh * 32 + c * 8 + 4 * half) = v4;
                }
    }
    __syncthreads();
    if (kw == 2) {
#pragma unroll
        for (int oh = 0; oh < 2; ++oh)
#pragma unroll
            for (int ph = 0; ph < 2; ++ph)
#pragma unroll
                for (int c = 0; c < 4; ++c) {
                    float* rp = red + (ph * 32 + l32) * 68 + oh * 32 + c * 8 + 4 * half;
                    floatx4 v4 = *(floatx4*)rp;
                    v4[0] += acc[oh][ph][4*c+0]; v4[1] += acc[oh][ph][4*c+1];
                    v4[2] += acc[oh][ph][4*c+2]; v4[3] += acc[oh][ph][4*c+3];
                    *(floatx4*)rp = v4;
                }
    }
    __syncthreads();
    if (kw == 1) {
#pragma unroll
        for (int oh = 0; oh < 2; ++oh)
#pragma unroll
            for (int ph = 0; ph < 2; ++ph)
#pragma unroll
                for (int c = 0; c < 4; ++c) {
                    float* rp = red + (ph * 32 + l32) * 68 + oh * 32 + c * 8 + 4 * half;
                    floatx4 v4 = *(floatx4*)rp;
                    v4[0] += acc[oh][ph][4*c+0]; v4[1] += acc[oh][ph][4*c+1];
                    v4[2] += acc[oh][ph][4*c+2]; v4[3] += acc[oh][ph][4*c+3];
                    *(floatx4*)rp = v4;
                }
    }
    __syncthreads();
    if (kw == 0) {
#pragma unroll
        for (int oh = 0; oh < 2; ++oh)
#pragma unroll
            for (int c = 0; c < 4; ++c) {
                const int ob = o0 + oh * 32 + c * 8 + 4 * half;
                const float4 bv = *(const float4*)(bias + ob);
#pragma unroll
                for (int ph = 0; ph < 2; ++ph) {
                    const int p = p0 + ph * 32 + l32;
                    floatx4 v4 = *(floatx4*)(red + (ph * 32 + l32) * 68 + oh * 32 + c * 8 + 4 * half);
                    if (p < PP) {
                        out[((size_t)(b * OO + ob + 0)) * PP + p] = v4[0] + acc[oh][ph][4*c+0] + bv.x;
                        out[((size_t)(b * OO + ob + 1)) * PP + p] = v4[1] + acc[oh][ph][4*c+1] + bv.y;
                        out[((size_t)(b * OO + ob + 2)) * PP + p] = v4[2] + acc[oh][ph][4*c+2] + bv.z;
                        out[((size_t)(b * OO + ob + 3)) * PP + p] = v4[3] + acc[oh][ph][4*c+3] + bv.w;
                    }
                }
            }
    }
}

// ---------------------------------------------------------------------------
// Last-resort fallback: naive but correct (ws too small).
// ---------------------------------------------------------------------------
__global__ __launch_bounds__(256) void dwconv_naive(
        const float* __restrict__ x, const float* __restrict__ kern,
        const float* __restrict__ w, const float* __restrict__ bias,
        float* __restrict__ out) {
    const int idx = blockIdx.x * 256 + threadIdx.x;
    if (idx >= BB * OO * PP) return;
    const int p = idx % PP;
    const int o = (idx / PP) % OO;
    const int b = idx / (PP * OO);
    const int h = p / HO;
    const int wq = p - h * HO;
    float acc = 0.f;
    for (int c = 0; c < CC; ++c) {
        const float* xp = x + ((size_t)(b * CC + c)) * (HH * WW) + h * WW + wq;
        const float* kp = kern + ((size_t)b * CC + c) * SS;
        const float* wp = w + ((size_t)o * CC + c) * SS;
#pragma unroll
        for (int s = 0; s < SS; ++s) {
            const int kk = s / KS;
            const int ll = s - kk * KS;
            acc += xp[kk * WW + ll] * kp[s] * wp[s];
        }
    }
    out[idx] = acc + bias[o];
}

extern "C" void kernel_launch(void* const* d_in, const int* in_sizes, int n_in,
                              void* d_out, int out_size, void* d_ws, size_t ws_size,
                              hipStream_t stream) {
    const float* x    = (const float*)d_in[0];
    const float* kern = (const float*)d_in[1];
    const float* w    = (const float*)d_in[2];
    const float* bias = (const float*)d_in[3];
    float* out = (float*)d_out;

    if (ws_size >= WT4_BYTES + WMOD_BYTES) {
        unsigned short* wt4  = (unsigned short*)d_ws;
        unsigned short* wmod = (unsigned short*)((char*)d_ws + WT4_BYTES);
        repack_w<<<dim3(SS * 8), dim3(256), 0, stream>>>(w, wt4);
        premod<<<dim3(BB * SS), dim3(256), 0, stream>>>(wt4, kern, wmod);
        dwconv_big<<<dim3(1280), dim3(256), 0, stream>>>(x, wmod, bias, out);
    } else {
        const int total = BB * OO * PP;
        dwconv_naive<<<dim3((total + 255) / 256), dim3(256), 0, stream>>>(
            x, kern, w, bias, out);
    }
}

// Round 10
// 349.656 us; speedup vs baseline: 1.1731x; 1.1731x over previous
//
#include <hip/hip_runtime.h>
#include <hip/hip_fp16.h>

typedef _Float16 half8 __attribute__((ext_vector_type(8)));
typedef __attribute__((ext_vector_type(4)))  float floatx4;
typedef __attribute__((ext_vector_type(16))) float floatx16;

#define BB 32
#define CC 256
#define OO 256
#define KS 7
#define HH 31
#define WW 31
#define HO 25
#define PP 625
#define SS 49

#define SLAB_PITCH 36        // ushort elems per pos row: 32 ci + 4 pad = 72 B
#define SLAB_ROWS  310       // 64-p tile spans <= 10 x-rows; 10 x 31 = 310
#define KPD 20               // klds pitch in dwords (16 half2 + 4 pad)

// wt4 layout: [s][cb][kh][o][16ci]  (elems per (s,cb) = 2*256*16 = 8192)
#define WT4_ELEMS  ((size_t)SS * 8 * 2 * CC * 16)        // 3,211,264
#define WT4_BYTES  (WT4_ELEMS * 2)                       // 6,422,528

static __device__ __forceinline__ unsigned pk2h(float lo, float hi) {
    __half2 h = __floats2half2_rn(lo, hi);    // v_cvt_pkrtz_f16_f32
    unsigned r;
    __builtin_memcpy(&r, &h, sizeof(r));
    return r;
}
static __device__ __forceinline__ unsigned mulh2(unsigned a, unsigned b) {
    __half2 x, y;
    __builtin_memcpy(&x, &a, 4); __builtin_memcpy(&y, &b, 4);
    __half2 r = __hmul2(x, y);                // v_pk_mul_f16
    unsigned u;
    __builtin_memcpy(&u, &r, 4);
    return u;
}
// modulated fragment: 8 fp16 = v[j] * k[j] via 4x v_pk_mul_f16
static __device__ __forceinline__ half8 mod8(half8 v, uint4 k) {
    uint4 w = __builtin_bit_cast(uint4, v);
    uint4 r;
    r.x = mulh2(w.x, k.x); r.y = mulh2(w.y, k.y);
    r.z = mulh2(w.z, k.z); r.w = mulh2(w.w, k.w);
    return __builtin_bit_cast(half8, r);
}

// ---------------------------------------------------------------------------
// Prepass: w[o][c][s] f32 -> wt4[s][cb][kh][o][16] fp16. Grid 392.
// ---------------------------------------------------------------------------
__global__ __launch_bounds__(256) void repack_w(const float* __restrict__ w,
                                                unsigned short* __restrict__ wt4) {
    const int bid = blockIdx.x;           // = s*8 + cb
    const int s = bid >> 3, cb = bid & 7;
    const int o = threadIdx.x;
    const float* src = w + ((size_t)o * CC + cb * 32) * SS + s;
    float v[32];
#pragma unroll
    for (int ci = 0; ci < 32; ++ci) v[ci] = src[(size_t)ci * SS];
#pragma unroll
    for (int kh = 0; kh < 2; ++kh) {
        unsigned short* dst = wt4 + ((size_t)bid * 2 + kh) * (CC * 16) + o * 16;
        uint4 p0, p1;
        p0.x = pk2h(v[kh*16+0], v[kh*16+1]);  p0.y = pk2h(v[kh*16+2], v[kh*16+3]);
        p0.z = pk2h(v[kh*16+4], v[kh*16+5]);  p0.w = pk2h(v[kh*16+6], v[kh*16+7]);
        p1.x = pk2h(v[kh*16+8], v[kh*16+9]);  p1.y = pk2h(v[kh*16+10], v[kh*16+11]);
        p1.z = pk2h(v[kh*16+12], v[kh*16+13]); p1.w = pk2h(v[kh*16+14], v[kh*16+15]);
        *(uint4*)(dst)     = p0;
        *(uint4*)(dst + 8) = p1;
    }
}

// ---------------------------------------------------------------------------
// Main (R2-verified 177us structure; modulation moved to the B operand):
// block = 64o x 64p, 4 waves k-split (s quarters). Per s-step per wave:
// 4 global b128 A from wt4 — MFMA consumes the loaded register DIRECTLY
// (the property shared by every >30%-MfmaUtil config; A-side modulation
// (R4/R7) put pk_mul between the global load and MFMA and stalled <27%).
// wt4 is b-independent: per-XCD oy-slice = 1.6 MB, truly L2-resident —
// eliminates premod (~57us) and the 205 MB wmod write+read entirely.
// B: 4 ds b128 + 2 ds b128 k-broadcast + 16 v_pk_mul_f16 — the mod now
// hangs off the ~120cy LDS path R2 already absorbed at 177us.
// 1-deep single-buffer A prefetch (R9's 2-deep rotation cost ~100us);
// pitch 36 (R5/R9-verified 0-conflict); lb(256,3) (mod +regs; lb4 would
// spill at the 128-reg cap). Grid 1280, same id decode + kw epilogue.
// ---------------------------------------------------------------------------
__global__ __launch_bounds__(256, 3) void dwconv_big(
        const float* __restrict__ x, const unsigned short* __restrict__ wt4,
        const float* __restrict__ kern, const float* __restrict__ bias,
        float* __restrict__ out) {
    __shared__ unsigned short slab[SLAB_ROWS * SLAB_PITCH];   // 22320 B
    __shared__ unsigned klds[SS * KPD];                       // 3920 B

    const int tid = threadIdx.x;
    const int id = blockIdx.x;
    // id = hi*80 + px*8 + g7; g = hi*8 + g7 = b*4 + oy -> same-XCD groups
    const int hi = id / 80, rem = id % 80;
    const int px = rem >> 3;
    const int g = hi * 8 + (rem & 7);
    const int b = g >> 2, oy = g & 3;

    const int p0 = px * 64, o0 = oy * 64;
    const int h0 = p0 / HO;
    const int pmax = (p0 + 63 < PP - 1) ? p0 + 63 : PP - 1;
    const int rows = pmax / HO - h0 + 7;          // <= 10
    const int npos = rows * WW;

    const int lane = tid & 63, kw = tid >> 6;
    const int l32 = lane & 31, half = lane >> 5;

    // B-fragment LDS offsets (ushort elems) for 2 p-subtiles of 32
    int bOff[2];
#pragma unroll
    for (int ph = 0; ph < 2; ++ph) {
        int p = p0 + ph * 32 + l32;
        if (p > PP - 1) p = PP - 1;               // clamp; store guarded later
        int h = p / HO, ww_ = p - h * HO;
        bOff[ph] = ((h - h0) * WW + ww_) * SLAB_PITCH + half * 8;
    }

    const int s0 = kw * 12 + (kw > 0 ? 1 : 0);    // 0,13,25,37
    const int ns = kw ? 12 : 13;

    // A base: rows (o0 + oh*32 + l32); oh -> +512, kh -> +4096;
    // per-s stride 65536; per-cb offset cb*8192   (wt4[s][cb][kh][o][16])
    const unsigned short* wbase = wt4 + (size_t)(o0 + l32) * 16 + half * 8;

    floatx16 acc[2][2];
#pragma unroll
    for (int oh = 0; oh < 2; ++oh)
#pragma unroll
        for (int ph = 0; ph < 2; ++ph)
#pragma unroll
            for (int r = 0; r < 16; ++r) acc[oh][ph][r] = 0.f;

    for (int cb = 0; cb < 8; ++cb) {
        __syncthreads();   // prior compute done: slab/klds safe to overwrite
        // ---- stage x slab: slab[pos][ci] fp16, 4 waves x 8 channels ----
        {
            const float* xsrc = x + ((size_t)(b * CC + cb * 32 + kw * 8)) * (HH * WW)
                                  + h0 * WW;
#pragma unroll
            for (int it = 0; it < 5; ++it) {
                int pos = lane + it * 64;
                if (pos < npos) {
                    float v[8];
#pragma unroll
                    for (int j = 0; j < 8; ++j) v[j] = xsrc[j * (HH * WW) + pos];
                    uint4 pkt;
                    pkt.x = pk2h(v[0], v[1]); pkt.y = pk2h(v[2], v[3]);
                    pkt.z = pk2h(v[4], v[5]); pkt.w = pk2h(v[6], v[7]);
                    *(uint4*)(slab + pos * SLAB_PITCH + kw * 8) = pkt;
                }
            }
        }
        // ---- stage k table: klds[s][16 half2] for this (b, cb) ----
        {
            const float* ksrc = kern + ((size_t)(b * CC + cb * 32)) * SS;
#pragma unroll
            for (int it = 0; it < 4; ++it) {
                int f = tid + it * 256;
                if (f < 16 * SS) {
                    int s = f >> 4, pr = f & 15;
                    float v0 = ksrc[(size_t)(pr * 2) * SS + s];
                    float v1 = ksrc[(size_t)(pr * 2 + 1) * SS + s];
                    klds[s * KPD + pr] = pk2h(v0, v1);
                }
            }
        }
        __syncthreads();

        // rolling A pointer: frag(oh,kh) = aptr + oh*512 + kh*4096; +65536/s
        const unsigned short* aptr = wbase + (size_t)(s0 * 8 + cb) * 8192;

        uint4 wa0 = *(const uint4*)(aptr);          // oh0 kh0
        uint4 wa1 = *(const uint4*)(aptr + 512);    // oh1 kh0
        uint4 wa2 = *(const uint4*)(aptr + 4096);   // oh0 kh1
        uint4 wa3 = *(const uint4*)(aptr + 4608);   // oh1 kh1

        int s = s0, kk = s0 / KS, ll = s0 - (s0 / KS) * KS;
        for (int si = 0; si < ns; ++si) {
            // prefetch s+1 A-frags (1.6 MB L2-resident wt4 slice)
            uint4 wn0, wn1, wn2, wn3;
            if (si + 1 < ns) {
                aptr += 65536;
                wn0 = *(const uint4*)(aptr);
                wn1 = *(const uint4*)(aptr + 512);
                wn2 = *(const uint4*)(aptr + 4096);
                wn3 = *(const uint4*)(aptr + 4608);
            } else {
                wn0 = wa0; wn1 = wa1; wn2 = wa2; wn3 = wa3;
            }

            // k broadcast for this s (ci pairs: kh*8 + half*4 + 0..3)
            const unsigned* kp = klds + (size_t)s * KPD;
            uint4 kv0 = *(const uint4*)(kp + half * 4);        // kh0
            uint4 kv1 = *(const uint4*)(kp + 8 + half * 4);    // kh1

            const unsigned short* slabS = slab + (kk * WW + ll) * SLAB_PITCH;
            half8 xb00 = *(const half8*)(slabS + bOff[0]);        // ph0 kh0
            half8 xb01 = *(const half8*)(slabS + bOff[0] + 16);   // ph0 kh1
            half8 xb10 = *(const half8*)(slabS + bOff[1]);        // ph1 kh0
            half8 xb11 = *(const half8*)(slabS + bOff[1] + 16);   // ph1 kh1

            // B-side modulation: b = k * x (A stays MFMA-direct)
            half8 sb00 = mod8(xb00, kv0);
            half8 sb01 = mod8(xb01, kv1);
            half8 sb10 = mod8(xb10, kv0);
            half8 sb11 = mod8(xb11, kv1);

            half8 a00 = __builtin_bit_cast(half8, wa0);  // oh0 kh0
            half8 a10 = __builtin_bit_cast(half8, wa1);  // oh1 kh0
            half8 a01 = __builtin_bit_cast(half8, wa2);  // oh0 kh1
            half8 a11 = __builtin_bit_cast(half8, wa3);  // oh1 kh1

            acc[0][0] = __builtin_amdgcn_mfma_f32_32x32x16_f16(a00, sb00, acc[0][0], 0, 0, 0);
            acc[0][1] = __builtin_amdgcn_mfma_f32_32x32x16_f16(a00, sb10, acc[0][1], 0, 0, 0);
            acc[1][0] = __builtin_amdgcn_mfma_f32_32x32x16_f16(a10, sb00, acc[1][0], 0, 0, 0);
            acc[1][1] = __builtin_amdgcn_mfma_f32_32x32x16_f16(a10, sb10, acc[1][1], 0, 0, 0);
            acc[0][0] = __builtin_amdgcn_mfma_f32_32x32x16_f16(a01, sb01, acc[0][0], 0, 0, 0);
            acc[0][1] = __builtin_amdgcn_mfma_f32_32x32x16_f16(a01, sb11, acc[0][1], 0, 0, 0);
            acc[1][0] = __builtin_amdgcn_mfma_f32_32x32x16_f16(a11, sb01, acc[1][0], 0, 0, 0);
            acc[1][1] = __builtin_amdgcn_mfma_f32_32x32x16_f16(a11, sb11, acc[1][1], 0, 0, 0);

            wa0 = wn0; wa1 = wn1; wa2 = wn2; wa3 = wn3;
            ++s; if (++ll == KS) { ll = 0; ++kk; }
        }
    }

    // ---- epilogue: 4-way kw reduction via LDS (reuse slab as red[64p][68]) --
    float* red = (float*)slab;
    __syncthreads();
    if (kw == 3) {
#pragma unroll
        for (int oh = 0; oh < 2; ++oh)
#pragma unroll
            for (int ph = 0; ph < 2; ++ph)
#pragma unroll
                for (int c = 0; c < 4; ++c) {
                    floatx4 v4 = {acc[oh][ph][4*c+0], acc[oh][ph][4*c+1],
                                  acc[oh][ph][4*c+2], acc[oh][ph][4*c+3]};
                    *(floatx4*)(red + (ph * 32 + l32) * 68 + oh * 32 + c * 8 + 4 * half) = v4;
                }
    }
    __syncthreads();
    if (kw == 2) {
#pragma unroll
        for (int oh = 0; oh < 2; ++oh)
#pragma unroll
            for (int ph = 0; ph < 2; ++ph)
#pragma unroll
                for (int c = 0; c < 4; ++c) {
                    float* rp = red + (ph * 32 + l32) * 68 + oh * 32 + c * 8 + 4 * half;
                    floatx4 v4 = *(floatx4*)rp;
                    v4[0] += acc[oh][ph][4*c+0]; v4[1] += acc[oh][ph][4*c+1];
                    v4[2] += acc[oh][ph][4*c+2]; v4[3] += acc[oh][ph][4*c+3];
                    *(floatx4*)rp = v4;
                }
    }
    __syncthreads();
    if (kw == 1) {
#pragma unroll
        for (int oh = 0; oh < 2; ++oh)
#pragma unroll
            for (int ph = 0; ph < 2; ++ph)
#pragma unroll
                for (int c = 0; c < 4; ++c) {
                    float* rp = red + (ph * 32 + l32) * 68 + oh * 32 + c * 8 + 4 * half;
                    floatx4 v4 = *(floatx4*)rp;
                    v4[0] += acc[oh][ph][4*c+0]; v4[1] += acc[oh][ph][4*c+1];
                    v4[2] += acc[oh][ph][4*c+2]; v4[3] += acc[oh][ph][4*c+3];
                    *(floatx4*)rp = v4;
                }
    }
    __syncthreads();
    if (kw == 0) {
#pragma unroll
        for (int oh = 0; oh < 2; ++oh)
#pragma unroll
            for (int c = 0; c < 4; ++c) {
                const int ob = o0 + oh * 32 + c * 8 + 4 * half;
                const float4 bv = *(const float4*)(bias + ob);
#pragma unroll
                for (int ph = 0; ph < 2; ++ph) {
                    const int p = p0 + ph * 32 + l32;
                    floatx4 v4 = *(floatx4*)(red + (ph * 32 + l32) * 68 + oh * 32 + c * 8 + 4 * half);
                    if (p < PP) {
                        out[((size_t)(b * OO + ob + 0)) * PP + p] = v4[0] + acc[oh][ph][4*c+0] + bv.x;
                        out[((size_t)(b * OO + ob + 1)) * PP + p] = v4[1] + acc[oh][ph][4*c+1] + bv.y;
                        out[((size_t)(b * OO + ob + 2)) * PP + p] = v4[2] + acc[oh][ph][4*c+2] + bv.z;
                        out[((size_t)(b * OO + ob + 3)) * PP + p] = v4[3] + acc[oh][ph][4*c+3] + bv.w;
                    }
                }
            }
    }
}

// ---------------------------------------------------------------------------
// Last-resort fallback: naive but correct (ws too small for wt4).
// ---------------------------------------------------------------------------
__global__ __launch_bounds__(256) void dwconv_naive(
        const float* __restrict__ x, const float* __restrict__ kern,
        const float* __restrict__ w, const float* __restrict__ bias,
        float* __restrict__ out) {
    const int idx = blockIdx.x * 256 + threadIdx.x;
    if (idx >= BB * OO * PP) return;
    const int p = idx % PP;
    const int o = (idx / PP) % OO;
    const int b = idx / (PP * OO);
    const int h = p / HO;
    const int wq = p - h * HO;
    float acc = 0.f;
    for (int c = 0; c < CC; ++c) {
        const float* xp = x + ((size_t)(b * CC + c)) * (HH * WW) + h * WW + wq;
        const float* kp = kern + ((size_t)b * CC + c) * SS;
        const float* wp = w + ((size_t)o * CC + c) * SS;
#pragma unroll
        for (int s = 0; s < SS; ++s) {
            const int kk = s / KS;
            const int ll = s - kk * KS;
            acc += xp[kk * WW + ll] * kp[s] * wp[s];
        }
    }
    out[idx] = acc + bias[o];
}

extern "C" void kernel_launch(void* const* d_in, const int* in_sizes, int n_in,
                              void* d_out, int out_size, void* d_ws, size_t ws_size,
                              hipStream_t stream) {
    const float* x    = (const float*)d_in[0];
    const float* kern = (const float*)d_in[1];
    const float* w    = (const float*)d_in[2];
    const float* bias = (const float*)d_in[3];
    float* out = (float*)d_out;

    if (ws_size >= WT4_BYTES) {
        unsigned short* wt4 = (unsigned short*)d_ws;
        repack_w<<<dim3(SS * 8), dim3(256), 0, stream>>>(w, wt4);
        dwconv_big<<<dim3(1280), dim3(256), 0, stream>>>(x, wt4, kern, bias, out);
    } else {
        const int total = BB * OO * PP;
        dwconv_naive<<<dim3((total + 255) / 256), dim3(256), 0, stream>>>(
            x, kern, w, bias, out);
    }
}